// Round 1
// baseline (1855.816 us; speedup 1.0000x reference)
//
#include <hip/hip_runtime.h>

// Problem constants (match reference)
#define NN   6
#define CC   80
#define DD   118
#define HH   32
#define WW   88
#define DHW  (DD * HH * WW)          // 332288
#define NDHW (NN * DHW)              // 1993728
#define MM   1036800
#define BH   360
#define BW   360
#define KK   (BH * BW)               // 129600

// ---------------------------------------------------------------------------
// NEW PATH: weighted transpose + row-gather pool.
//
// cft[i*80 + c] = cf[n*C*DHW + c*DHW + rem] * dw[i], i = n*DHW + rem.
// After this, each point's 80 channels are ONE contiguous 320 B row
// (5 fully-used 64 B lines) instead of 80 strided 4 B touches across an
// 8 MB random working set. Converts the 3.95 GB over-fetch into 638 MB
// sequential + 332 MB fully-utilized row reads.
// ---------------------------------------------------------------------------

// Kernel T: thread handles 4 consecutive i (DHW % 4 == 0, so all 4 share n).
// Reads: per c, float4 across lanes = 1 KiB/wave contiguous (perfect).
// Writes: 4 rows x float4 chunks; L2 write-back merges the 320B-stride
// partial lines (4 float4 stores land in each 64B line before eviction).
__global__ __launch_bounds__(256) void bev_transpose(const float* __restrict__ cf,
                                                     const float* __restrict__ dw,
                                                     float* __restrict__ cft) {
    int t = blockIdx.x * 256 + threadIdx.x;
    int i0 = t * 4;
    if (i0 >= NDHW) return;
    unsigned n = (unsigned)i0 / (unsigned)DHW;         // const divisor -> magic mul
    unsigned rem = (unsigned)i0 - n * (unsigned)DHW;
    const float* __restrict__ src = cf + (size_t)n * (size_t)(CC * DHW) + rem;
    float4 w = *reinterpret_cast<const float4*>(dw + i0);
    float* __restrict__ r = cft + (size_t)i0 * CC;
    #pragma unroll 2
    for (int c0 = 0; c0 < CC; c0 += 4) {
        float4 a  = *reinterpret_cast<const float4*>(src + (size_t)(c0 + 0) * DHW);
        float4 b  = *reinterpret_cast<const float4*>(src + (size_t)(c0 + 1) * DHW);
        float4 cc = *reinterpret_cast<const float4*>(src + (size_t)(c0 + 2) * DHW);
        float4 d  = *reinterpret_cast<const float4*>(src + (size_t)(c0 + 3) * DHW);
        *reinterpret_cast<float4*>(r + 0 * CC + c0) = make_float4(a.x * w.x, b.x * w.x, cc.x * w.x, d.x * w.x);
        *reinterpret_cast<float4*>(r + 1 * CC + c0) = make_float4(a.y * w.y, b.y * w.y, cc.y * w.y, d.y * w.y);
        *reinterpret_cast<float4*>(r + 2 * CC + c0) = make_float4(a.z * w.z, b.z * w.z, cc.z * w.z, d.z * w.z);
        *reinterpret_cast<float4*>(r + 3 * CC + c0) = make_float4(a.w * w.w, b.w * w.w, cc.w * w.w, d.w * w.w);
    }
}

// Kernel P: block (80, 8) — x = channel lane, y = bev cell. Each point's row
// read is 320 B contiguous, 64B-aligned (320 = 5*64). Weight already folded.
__global__ __launch_bounds__(640) void bev_pool_t(const float* __restrict__ cft,
                                                  const int* __restrict__ indices,
                                                  const int* __restrict__ intervals,
                                                  float* __restrict__ out) {
    int c = threadIdx.x;                          // 0..79
    int k = blockIdx.x * 8 + threadIdx.y;
    if (k >= KK) return;
    int s = intervals[3 * k];
    int e = intervals[3 * k + 1];
    int b = intervals[3 * k + 2];
    float acc = 0.f;
    int len = e - s;
    if (len == 8) {
        const int* __restrict__ ip = indices + s;
        int i0 = ip[0], i1 = ip[1], i2 = ip[2], i3 = ip[3];
        int i4 = ip[4], i5 = ip[5], i6 = ip[6], i7 = ip[7];
        float f0 = cft[(size_t)i0 * CC + c], f1 = cft[(size_t)i1 * CC + c];
        float f2 = cft[(size_t)i2 * CC + c], f3 = cft[(size_t)i3 * CC + c];
        float f4 = cft[(size_t)i4 * CC + c], f5 = cft[(size_t)i5 * CC + c];
        float f6 = cft[(size_t)i6 * CC + c], f7 = cft[(size_t)i7 * CC + c];
        acc = ((((((f0 + f1) + f2) + f3) + f4) + f5) + f6) + f7;   // ascending p, matches ref order
    } else {
        for (int p = s; p < e; ++p)
            acc += cft[(size_t)indices[p] * CC + c];
    }
    out[(size_t)c * KK + b] = acc;
}

// ---------------------------------------------------------------------------
// FALLBACK PATHS (previous verified kernels) — used when workspace is small.
// ---------------------------------------------------------------------------

__global__ __launch_bounds__(256) void bev_prep(const int* __restrict__ indices,
                                                const float* __restrict__ dw,
                                                int2* __restrict__ pw) {
    int p = blockIdx.x * 256 + threadIdx.x;
    if (p >= MM) return;
    int i = indices[p];
    unsigned ui = (unsigned)i;
    unsigned n = ui / (unsigned)DHW;
    unsigned rem = ui - n * (unsigned)DHW;
    float w = dw[i];
    pw[p] = make_int2((int)(n * (unsigned)(CC * DHW) + rem), __float_as_int(w));
}

__global__ __launch_bounds__(256) void bev_pool(const float* __restrict__ cf,
                                                const int2* __restrict__ pw,
                                                const int* __restrict__ intervals,
                                                float* __restrict__ out) {
    int t = blockIdx.x * 256 + threadIdx.x;
    if (t >= CC * KK) return;
    int k = t % KK;
    int c = t / KK;
    int s = intervals[3 * k];
    int e = intervals[3 * k + 1];
    int b = intervals[3 * k + 2];
    const float* __restrict__ cfc = cf + (size_t)c * DHW;
    float acc = 0.f;
    int len = e - s;
    if (len == 8) {
        int2 v0 = pw[s + 0]; int2 v1 = pw[s + 1]; int2 v2 = pw[s + 2]; int2 v3 = pw[s + 3];
        int2 v4 = pw[s + 4]; int2 v5 = pw[s + 5]; int2 v6 = pw[s + 6]; int2 v7 = pw[s + 7];
        float f0 = cfc[v0.x], f1 = cfc[v1.x], f2 = cfc[v2.x], f3 = cfc[v3.x];
        float f4 = cfc[v4.x], f5 = cfc[v5.x], f6 = cfc[v6.x], f7 = cfc[v7.x];
        acc = __int_as_float(v0.y) * f0 + __int_as_float(v1.y) * f1
            + __int_as_float(v2.y) * f2 + __int_as_float(v3.y) * f3
            + __int_as_float(v4.y) * f4 + __int_as_float(v5.y) * f5
            + __int_as_float(v6.y) * f6 + __int_as_float(v7.y) * f7;
    } else {
        for (int p = s; p < e; ++p) {
            int2 v = pw[p];
            acc += __int_as_float(v.y) * cfc[v.x];
        }
    }
    out[(size_t)c * KK + b] = acc;
}

__global__ __launch_bounds__(256) void bev_pool_inline(const float* __restrict__ cf,
                                                       const float* __restrict__ dw,
                                                       const int* __restrict__ indices,
                                                       const int* __restrict__ intervals,
                                                       float* __restrict__ out) {
    int t = blockIdx.x * 256 + threadIdx.x;
    if (t >= CC * KK) return;
    int k = t % KK;
    int c = t / KK;
    int s = intervals[3 * k];
    int e = intervals[3 * k + 1];
    int b = intervals[3 * k + 2];
    const float* __restrict__ cfc = cf + (size_t)c * DHW;
    float acc = 0.f;
    for (int p = s; p < e; ++p) {
        int i = indices[p];
        unsigned ui = (unsigned)i;
        unsigned n = ui / (unsigned)DHW;
        unsigned rem = ui - n * (unsigned)DHW;
        acc += dw[i] * cfc[n * (unsigned)(CC * DHW) + rem];
    }
    out[(size_t)c * KK + b] = acc;
}

extern "C" void kernel_launch(void* const* d_in, const int* in_sizes, int n_in,
                              void* d_out, int out_size, void* d_ws, size_t ws_size,
                              hipStream_t stream) {
    const float* cf        = (const float*)d_in[0];
    const float* dw        = (const float*)d_in[1];
    const int*   indices   = (const int*)d_in[2];
    const int*   intervals = (const int*)d_in[3];
    float* out = (float*)d_out;

    const size_t cft_bytes = (size_t)NDHW * CC * sizeof(float);   // ~608 MiB

    if (ws_size >= cft_bytes) {
        float* cft = (float*)d_ws;
        // transpose+weight: NDHW/4 threads, exact grid (NDHW = 4*256*1947)
        bev_transpose<<<(NDHW / 4 + 255) / 256, 256, 0, stream>>>(cf, dw, cft);
        dim3 blk(80, 8, 1);
        bev_pool_t<<<(KK + 7) / 8, blk, 0, stream>>>(cft, indices, intervals, out);
    } else if (ws_size >= (size_t)MM * sizeof(int2)) {
        const int total = CC * KK;
        const int poolBlocks = (total + 255) / 256;
        int2* pw = (int2*)d_ws;
        bev_prep<<<(MM + 255) / 256, 256, 0, stream>>>(indices, dw, pw);
        bev_pool<<<poolBlocks, 256, 0, stream>>>(cf, pw, intervals, out);
    } else {
        const int total = CC * KK;
        const int poolBlocks = (total + 255) / 256;
        bev_pool_inline<<<poolBlocks, 256, 0, stream>>>(cf, dw, indices, intervals, out);
    }
}

// Round 2
// 1061.630 us; speedup vs baseline: 1.7481x; 1.7481x over previous
//
#include <hip/hip_runtime.h>

// Problem constants (match reference)
#define NN   6
#define CC   80
#define DD   118
#define HH   32
#define WW   88
#define DHW  (DD * HH * WW)          // 332288
#define NDHW (NN * DHW)              // 1993728
#define MM   1036800
#define BH   360
#define BW   360
#define KK   (BH * BW)               // 129600

#define TI          64               // i-tile per block
#define TILES_PER_N (DHW / TI)       // 5192 (exact)

// ---------------------------------------------------------------------------
// Weighted transpose via LDS staging.
// cft[i*80 + c] = cf[n*C*DHW + c*DHW + rem] * dw[i],  i = n*DHW + rem.
//
// Round-1 version stored float4s at 1280B inter-lane stride: every wave
// store dirtied 64 lines x 16B -> partial-line RMW, 0.61 TB/s write.
// This version stages the 80x64 tile in LDS and writes ONE contiguous
// 20480B block per workgroup (full lines, streaming).
// ---------------------------------------------------------------------------
__global__ __launch_bounds__(256) void bev_transpose_lds(const float* __restrict__ cf,
                                                         const float* __restrict__ dw,
                                                         float* __restrict__ cft) {
    __shared__ float lds[TI][81];    // [i_local][c], pad 81 -> <=2-way conflicts (free)
    __shared__ float wl[TI];

    int bid = blockIdx.x;
    int n    = bid / TILES_PER_N;                 // const divisor -> magic mul
    int tile = bid - n * TILES_PER_N;
    int i0l  = tile * TI;                         // i offset within this n

    const float* __restrict__ src = cf + (size_t)n * (size_t)(CC * DHW) + i0l;
    int t = threadIdx.x;

    // stage the 64 depth-weights for this tile
    if (t < TI / 4) {
        float4 w4 = *reinterpret_cast<const float4*>(dw + (size_t)n * DHW + i0l + t * 4);
        wl[t * 4 + 0] = w4.x; wl[t * 4 + 1] = w4.y;
        wl[t * 4 + 2] = w4.z; wl[t * 4 + 3] = w4.w;
    }

    // read phase: 80 c-rows x 16 float4 = 1280 float4, coalesced 256B segments
    #pragma unroll
    for (int it = 0; it < 5; ++it) {
        int idx = it * 256 + t;                   // 0..1279
        int c = idx >> 4;                         // 0..79
        int f = idx & 15;                         // float4 slot within row
        float4 v = *reinterpret_cast<const float4*>(src + (size_t)c * DHW + f * 4);
        lds[f * 4 + 0][c] = v.x;
        lds[f * 4 + 1][c] = v.y;
        lds[f * 4 + 2][c] = v.z;
        lds[f * 4 + 3][c] = v.w;
    }
    __syncthreads();

    // write phase: 20480B contiguous block, weight folded in.
    // 80 floats/row = 20 float4/row, float4 never straddles a row.
    float* __restrict__ dst = cft + ((size_t)n * DHW + i0l) * CC;
    #pragma unroll
    for (int it = 0; it < 5; ++it) {
        int idx = it * 256 + t;                   // float4 index 0..1279
        int j = idx / 20;                         // i_local
        int q = idx - j * 20;
        int c0 = q * 4;
        float w = wl[j];
        float4 v = make_float4(lds[j][c0 + 0] * w, lds[j][c0 + 1] * w,
                               lds[j][c0 + 2] * w, lds[j][c0 + 3] * w);
        *reinterpret_cast<float4*>(dst + (size_t)idx * 4) = v;
    }
}

// Pool: block (80, 8) — x = channel lane, y = bev cell. Each point's row
// read is 320 B contiguous, 64B-aligned (320 = 5*64). Weight already folded.
__global__ __launch_bounds__(640) void bev_pool_t(const float* __restrict__ cft,
                                                  const int* __restrict__ indices,
                                                  const int* __restrict__ intervals,
                                                  float* __restrict__ out) {
    int c = threadIdx.x;                          // 0..79
    int k = blockIdx.x * 8 + threadIdx.y;
    if (k >= KK) return;
    int s = intervals[3 * k];
    int e = intervals[3 * k + 1];
    int b = intervals[3 * k + 2];
    float acc = 0.f;
    int len = e - s;
    if (len == 8) {
        const int* __restrict__ ip = indices + s;
        int i0 = ip[0], i1 = ip[1], i2 = ip[2], i3 = ip[3];
        int i4 = ip[4], i5 = ip[5], i6 = ip[6], i7 = ip[7];
        float f0 = cft[(size_t)i0 * CC + c], f1 = cft[(size_t)i1 * CC + c];
        float f2 = cft[(size_t)i2 * CC + c], f3 = cft[(size_t)i3 * CC + c];
        float f4 = cft[(size_t)i4 * CC + c], f5 = cft[(size_t)i5 * CC + c];
        float f6 = cft[(size_t)i6 * CC + c], f7 = cft[(size_t)i7 * CC + c];
        acc = ((((((f0 + f1) + f2) + f3) + f4) + f5) + f6) + f7;   // ascending p, matches ref order
    } else {
        for (int p = s; p < e; ++p)
            acc += cft[(size_t)indices[p] * CC + c];
    }
    out[(size_t)c * KK + b] = acc;
}

// ---------------------------------------------------------------------------
// FALLBACK PATHS (previous verified kernels) — used when workspace is small.
// ---------------------------------------------------------------------------

__global__ __launch_bounds__(256) void bev_prep(const int* __restrict__ indices,
                                                const float* __restrict__ dw,
                                                int2* __restrict__ pw) {
    int p = blockIdx.x * 256 + threadIdx.x;
    if (p >= MM) return;
    int i = indices[p];
    unsigned ui = (unsigned)i;
    unsigned n = ui / (unsigned)DHW;
    unsigned rem = ui - n * (unsigned)DHW;
    float w = dw[i];
    pw[p] = make_int2((int)(n * (unsigned)(CC * DHW) + rem), __float_as_int(w));
}

__global__ __launch_bounds__(256) void bev_pool(const float* __restrict__ cf,
                                                const int2* __restrict__ pw,
                                                const int* __restrict__ intervals,
                                                float* __restrict__ out) {
    int t = blockIdx.x * 256 + threadIdx.x;
    if (t >= CC * KK) return;
    int k = t % KK;
    int c = t / KK;
    int s = intervals[3 * k];
    int e = intervals[3 * k + 1];
    int b = intervals[3 * k + 2];
    const float* __restrict__ cfc = cf + (size_t)c * DHW;
    float acc = 0.f;
    int len = e - s;
    if (len == 8) {
        int2 v0 = pw[s + 0]; int2 v1 = pw[s + 1]; int2 v2 = pw[s + 2]; int2 v3 = pw[s + 3];
        int2 v4 = pw[s + 4]; int2 v5 = pw[s + 5]; int2 v6 = pw[s + 6]; int2 v7 = pw[s + 7];
        float f0 = cfc[v0.x], f1 = cfc[v1.x], f2 = cfc[v2.x], f3 = cfc[v3.x];
        float f4 = cfc[v4.x], f5 = cfc[v5.x], f6 = cfc[v6.x], f7 = cfc[v7.x];
        acc = __int_as_float(v0.y) * f0 + __int_as_float(v1.y) * f1
            + __int_as_float(v2.y) * f2 + __int_as_float(v3.y) * f3
            + __int_as_float(v4.y) * f4 + __int_as_float(v5.y) * f5
            + __int_as_float(v6.y) * f6 + __int_as_float(v7.y) * f7;
    } else {
        for (int p = s; p < e; ++p) {
            int2 v = pw[p];
            acc += __int_as_float(v.y) * cfc[v.x];
        }
    }
    out[(size_t)c * KK + b] = acc;
}

__global__ __launch_bounds__(256) void bev_pool_inline(const float* __restrict__ cf,
                                                       const float* __restrict__ dw,
                                                       const int* __restrict__ indices,
                                                       const int* __restrict__ intervals,
                                                       float* __restrict__ out) {
    int t = blockIdx.x * 256 + threadIdx.x;
    if (t >= CC * KK) return;
    int k = t % KK;
    int c = t / KK;
    int s = intervals[3 * k];
    int e = intervals[3 * k + 1];
    int b = intervals[3 * k + 2];
    const float* __restrict__ cfc = cf + (size_t)c * DHW;
    float acc = 0.f;
    for (int p = s; p < e; ++p) {
        int i = indices[p];
        unsigned ui = (unsigned)i;
        unsigned n = ui / (unsigned)DHW;
        unsigned rem = ui - n * (unsigned)DHW;
        acc += dw[i] * cfc[n * (unsigned)(CC * DHW) + rem];
    }
    out[(size_t)c * KK + b] = acc;
}

extern "C" void kernel_launch(void* const* d_in, const int* in_sizes, int n_in,
                              void* d_out, int out_size, void* d_ws, size_t ws_size,
                              hipStream_t stream) {
    const float* cf        = (const float*)d_in[0];
    const float* dw        = (const float*)d_in[1];
    const int*   indices   = (const int*)d_in[2];
    const int*   intervals = (const int*)d_in[3];
    float* out = (float*)d_out;

    const size_t cft_bytes = (size_t)NDHW * CC * sizeof(float);   // ~608 MiB

    if (ws_size >= cft_bytes) {
        float* cft = (float*)d_ws;
        bev_transpose_lds<<<NN * TILES_PER_N, 256, 0, stream>>>(cf, dw, cft);
        dim3 blk(80, 8, 1);
        bev_pool_t<<<(KK + 7) / 8, blk, 0, stream>>>(cft, indices, intervals, out);
    } else if (ws_size >= (size_t)MM * sizeof(int2)) {
        const int total = CC * KK;
        const int poolBlocks = (total + 255) / 256;
        int2* pw = (int2*)d_ws;
        bev_prep<<<(MM + 255) / 256, 256, 0, stream>>>(indices, dw, pw);
        bev_pool<<<poolBlocks, 256, 0, stream>>>(cf, pw, intervals, out);
    } else {
        const int total = CC * KK;
        const int poolBlocks = (total + 255) / 256;
        bev_pool_inline<<<poolBlocks, 256, 0, stream>>>(cf, dw, indices, intervals, out);
    }
}